// Round 12
// baseline (294.608 us; speedup 1.0000x reference)
//
#include <hip/hip_runtime.h>

#define DN 96
#define FIN 128

typedef unsigned int uint_t;
typedef unsigned short ushort_t;

typedef __attribute__((ext_vector_type(8))) short short8v;  // 8 bf16 (4 VGPRs)
typedef __attribute__((ext_vector_type(4))) float f32x4;

#define MFMA16 __builtin_amdgcn_mfma_f32_16x16x32_bf16

struct __align__(4) U3 { uint_t x, y, z; };

__device__ __forceinline__ ushort_t f2bf(float f) {
    uint_t u = __float_as_uint(f);
    uint_t r = (u + 0x7FFFu + ((u >> 16) & 1u)) >> 16;
    return (ushort_t)r;
}
__device__ __forceinline__ float bf2f(ushort_t h) { return __uint_as_float(((uint_t)h) << 16); }
__device__ __forceinline__ float bf_lo(uint_t u) { return __uint_as_float(u << 16); }
__device__ __forceinline__ float bf_hi(uint_t u) { return __uint_as_float(u & 0xFFFF0000u); }

__device__ __forceinline__ U3 ldrow(const uint_t* __restrict__ g, int idx, int j) {
    return *(const U3*)(g + (size_t)idx * 48 + 3 * j);
}
__device__ __forceinline__ void acc6(float* s, U3 v) {
    s[0] += bf_lo(v.x); s[1] += bf_hi(v.x);
    s[2] += bf_lo(v.y); s[3] += bf_hi(v.y);
    s[4] += bf_lo(v.z); s[5] += bf_hi(v.z);
}

// ---------- prep: kd build (atomics-free) + weight pack + zero rows, one launch ----------
// kdx[e] = dst | r<<16 ; kdy[e] = src (ushort, N < 65536).

__global__ __launch_bounds__(256) void prep_kernel(
    const int* __restrict__ ei, const float* __restrict__ ea,
    uint_t* __restrict__ kdx, ushort_t* __restrict__ kdy,
    const float* __restrict__ root, const float* __restrict__ W, const float* __restrict__ Wf,
    ushort_t* __restrict__ Bph, ushort_t* __restrict__ Bpl,
    ushort_t* __restrict__ Wfh, ushort_t* __restrict__ Wfl,
    ushort_t* g0A, ushort_t* g1A, ushort_t* g0B, ushort_t* g1B,
    int E, int N, int KD_BLKS)
{
    int bid = blockIdx.x;
    int t = threadIdx.x;
    if (bid < KD_BLKS) {
        int e = bid * 256 + t;
        if (e < E) {
            int src = ei[e];
            int dst = ei[E + e];
            float2 a = *(const float2*)(ea + 2 * e);
            int r = (a.y > a.x) ? 1 : 0;   // argmax over 2, first-max tie -> 0
            kdx[e] = (uint_t)dst | ((uint_t)r << 16);
            kdy[e] = (ushort_t)src;
        }
    } else if (bid < KD_BLKS + 78) {
        if (t >= 64) return;
        int l = t;
        int fid = bid - KD_BLKS;
        if (fid < 54) {
            int ct = fid / 3, ks = fid % 3;
            int mat = ct / 6, cw = ct % 6;
            const float* M = (mat == 0) ? root : (W + (size_t)(mat - 1) * DN * DN);
            int k0 = 32 * ks + (l >> 4) * 8;
            int col = 16 * cw + (l & 15);
#pragma unroll
            for (int j = 0; j < 8; j++) {
                float v = M[(size_t)(k0 + j) * DN + col];
                ushort_t h = f2bf(v);
                size_t idx = ((size_t)fid * 64 + l) * 8 + j;
                Bph[idx] = h;
                Bpl[idx] = f2bf(v - bf2f(h));
            }
        } else {
            int f2 = fid - 54;
            int ct = f2 >> 2, ks = f2 & 3;
            int k0 = 32 * ks + (l >> 4) * 8;
            int col = 16 * ct + (l & 15);
#pragma unroll
            for (int j = 0; j < 8; j++) {
                float v = Wf[(size_t)col * FIN + k0 + j];
                ushort_t h = f2bf(v);
                size_t idx = ((size_t)f2 * 64 + l) * 8 + j;
                Wfh[idx] = h;
                Wfl[idx] = f2bf(v - bf2f(h));
            }
        }
    } else {
        // zero row N of the 4 g tables (clamped-gather target)
        int pair = bid - (KD_BLKS + 78);   // 0 or 1
        ushort_t* ga = pair ? g0B : g0A;
        ushort_t* gb = pair ? g1B : g1A;
        if (t < 96) ga[(size_t)N * DN + t] = 0;
        else if (t < 192) gb[(size_t)N * DN + (t - 96)] = 0;
    }
}

// ---------- XCD-partitioned hist ----------

__global__ __launch_bounds__(256) void hist_part(const uint_t* __restrict__ kdx,
                                                 int* __restrict__ cnt, int E, int N, int PS) {
    int p = blockIdx.x & 7;
    int c = blockIdx.x >> 3;
    int base = c * 2048 + threadIdx.x;
#pragma unroll
    for (int i = 0; i < 8; i++) {
        int e = base + i * 256;
        if (e < E) {
            uint_t v = kdx[e];
            int dst = v & 0xFFFF;
            if (dst / PS == p) {
                int r = (v >> 16) & 1;
                atomicAdd(&cnt[r * N + dst], 1);
            }
        }
    }
}

__global__ void offsets_kernel(const int* __restrict__ cnt, int* __restrict__ total,
                               int* __restrict__ rowstart, int* __restrict__ fillptr,
                               int nbins) {
    __shared__ int sd[256];
    __shared__ int sbase;
    int t = threadIdx.x;
    int b = blockIdx.x * 256 + t;
    int v = (b < nbins) ? cnt[b] : 0;
    sd[t] = v;
    __syncthreads();
    for (int off = 1; off < 256; off <<= 1) {
        int add = (t >= off) ? sd[t - off] : 0;
        __syncthreads();
        sd[t] += add;
        __syncthreads();
    }
    if (t == 255) sbase = atomicAdd(total, sd[255]);
    __syncthreads();
    if (b < nbins) {
        int s = sbase + sd[t] - v;  // exclusive
        rowstart[b] = s;
        fillptr[b] = s;
    }
}

// ---------- XCD-partitioned fill, ushort srcs (halved scatter bytes) ----------

__global__ __launch_bounds__(256) void fill_part(const uint_t* __restrict__ kdx,
                            const ushort_t* __restrict__ kdy,
                            int* __restrict__ fillptr, ushort_t* __restrict__ srcs,
                            int E, int N, int PS) {
    int p = blockIdx.x & 7;
    int c = blockIdx.x >> 3;
    int base = c * 2048 + threadIdx.x;
#pragma unroll
    for (int i = 0; i < 8; i++) {
        int e = base + i * 256;
        if (e < E) {
            uint_t v = kdx[e];
            int dst = v & 0xFFFF;
            if (dst / PS == p) {
                int r = (v >> 16) & 1;
                int pos = atomicAdd(&fillptr[r * N + dst], 1);
                srcs[pos] = kdy[e];
            }
        }
    }
}

// ---------- split-bf16 A-fragment conversion ----------

__device__ __forceinline__ void cvt8(float4 x, float4 y, short8v& hi, short8v& lo) {
    union { short8v v; ushort_t u[8]; } H, L;
    float f[8] = {x.x, x.y, x.z, x.w, y.x, y.y, y.z, y.w};
#pragma unroll
    for (int j = 0; j < 8; j++) {
        ushort_t h = f2bf(f[j]);
        H.u[j] = h;
        L.u[j] = f2bf(f[j] - bf2f(h));
    }
    hi = H.v; lo = L.v;
}

// ---------- lin+gemm (layer 0): h = relu(x@Wf^T+bf) then gemm, 256 thr / 64 nodes ----------

__global__ __launch_bounds__(256) void lin_gemm(
    const float* __restrict__ xin,
    const ushort_t* __restrict__ WfH, const ushort_t* __restrict__ WfL,
    const ushort_t* __restrict__ Bph, const ushort_t* __restrict__ Bpl,
    const float* __restrict__ bfv, const float* __restrict__ bias,
    float* __restrict__ hrootOut, ushort_t* __restrict__ g0Out, ushort_t* __restrict__ g1Out,
    int N)
{
    __shared__ float sout[4][16][100];
    int t = threadIdx.x;
    int l = t & 63;
    int w = t >> 6;

    int slab = blockIdx.x * 64 + w * 16;
    int row = slab + (l & 15);
    if (row >= N) row = N - 1;
    const float* xrow = xin + (size_t)row * FIN + ((l >> 4) * 8);
    short8v ah4[4], al4[4];
#pragma unroll
    for (int ks = 0; ks < 4; ks++) {
        float4 xa = *(const float4*)(xrow + 32 * ks);
        float4 xb = *(const float4*)(xrow + 32 * ks + 4);
        cvt8(xa, xb, ah4[ks], al4[ks]);
    }
#pragma unroll
    for (int ct = 0; ct < 6; ct++) {
        f32x4 hh = {0.f,0.f,0.f,0.f}, hl_ = {0.f,0.f,0.f,0.f}, lh = {0.f,0.f,0.f,0.f};
#pragma unroll
        for (int ks = 0; ks < 4; ks++) {
            size_t base = ((size_t)(ct * 4 + ks) * 64 + l) * 8;
            short8v bh = *(const short8v*)(WfH + base);
            short8v bl = *(const short8v*)(WfL + base);
            hh  = MFMA16(ah4[ks], bh, hh, 0, 0, 0);
            hl_ = MFMA16(ah4[ks], bl, hl_, 0, 0, 0);
            lh  = MFMA16(al4[ks], bh, lh, 0, 0, 0);
        }
        f32x4 acc = hh + hl_ + lh;
        int col = ct * 16 + (l & 15);
        float bv = bfv[col];
        int lr0 = (l >> 4) * 4;
#pragma unroll
        for (int r = 0; r < 4; r++) {
            float v = acc[r] + bv;
            sout[w][lr0 + r][col] = v > 0.f ? v : 0.f;
        }
    }
    __syncthreads();

    const float* srow = &sout[w][l & 15][0];
    int mbase = blockIdx.x * 64 + w * 16 + ((l >> 4) << 2);
    int k0 = (l >> 4) * 8;
    short8v ah[3], al[3];
#pragma unroll
    for (int ks = 0; ks < 3; ks++) {
        float4 xa = *(const float4*)(srow + k0 + 32 * ks);
        float4 xb = *(const float4*)(srow + k0 + 32 * ks + 4);
        cvt8(xa, xb, ah[ks], al[ks]);
    }
    for (int ct = 0; ct < 18; ct++) {
        f32x4 hh = {0.f,0.f,0.f,0.f}, hl_ = {0.f,0.f,0.f,0.f}, lh = {0.f,0.f,0.f,0.f};
#pragma unroll
        for (int ks = 0; ks < 3; ks++) {
            size_t base = ((size_t)(ct * 3 + ks) * 64 + l) * 8;
            short8v bh = *(const short8v*)(Bph + base);
            short8v bl = *(const short8v*)(Bpl + base);
            hh  = MFMA16(ah[ks], bh, hh, 0, 0, 0);
            hl_ = MFMA16(ah[ks], bl, hl_, 0, 0, 0);
            lh  = MFMA16(al[ks], bh, lh, 0, 0, 0);
        }
        f32x4 acc = hh + hl_ + lh;
        int mat = ct / 6;
        int col = (ct % 6) * 16 + (l & 15);
        if (mat == 0) {
            float bv = bias[col];
#pragma unroll
            for (int r = 0; r < 4; r++) {
                int m = mbase + r;
                if (m < N) hrootOut[(size_t)m * DN + col] = acc[r] + bv;
            }
        } else {
            ushort_t* g = (mat == 1) ? g0Out : g1Out;
#pragma unroll
            for (int r = 0; r < 4; r++) {
                int m = mbase + r;
                if (m < N) g[(size_t)m * DN + col] = f2bf(acc[r]);
            }
        }
    }
}

// ---------- fused gather(+gemm) layer: 256 thr / 16 nodes ----------
// Gather: 16 groups of 16 lanes, one node each; uniform 8-batches clamped to
// the zero row N (no tail). srcs indices are ushort.

template <int GEMM>
__global__ __launch_bounds__(256) void layer_kernel(
    const float* __restrict__ hrootIn,
    const uint_t* __restrict__ g0In, const uint_t* __restrict__ g1In,
    const int* __restrict__ rowstart, const int* __restrict__ cnt,
    const ushort_t* __restrict__ srcs,
    const ushort_t* __restrict__ Bph, const ushort_t* __restrict__ Bpl,
    const float* __restrict__ bias,
    float* __restrict__ hrootOut, ushort_t* __restrict__ g0Out, ushort_t* __restrict__ g1Out,
    float* __restrict__ dout, int N)
{
    __shared__ float sout[16][100];   // pad breaks power-of-2 bank stride
    int t = threadIdx.x;

    // ---- gather phase ----
    {
        int grp = t >> 4;
        int j = t & 15;
        int n = blockIdx.x * 16 + grp;
        bool valid = n < N;
        int nc = valid ? n : N - 1;

        const float* hr = hrootIn + (size_t)nc * DN + 6 * j;
        float2 p0 = *(const float2*)hr;
        float2 p1 = *(const float2*)(hr + 2);
        float2 p2 = *(const float2*)(hr + 4);

        float a[6] = {0.f,0.f,0.f,0.f,0.f,0.f};
#pragma unroll
        for (int r = 0; r < 2; r++) {
            int c    = valid ? cnt[r * N + nc] : 0;
            int base = valid ? rowstart[r * N + nc] : 0;
            const uint_t* g = r ? g1In : g0In;
            const ushort_t* sp = srcs + base;
            float sA[6] = {0.f,0.f,0.f,0.f,0.f,0.f};
            float sB[6] = {0.f,0.f,0.f,0.f,0.f,0.f};
            for (int e = 0; e < c; e += 8) {
                int i0 = (e + 0 < c) ? (int)sp[e + 0] : N;
                int i1 = (e + 1 < c) ? (int)sp[e + 1] : N;
                int i2 = (e + 2 < c) ? (int)sp[e + 2] : N;
                int i3 = (e + 3 < c) ? (int)sp[e + 3] : N;
                int i4 = (e + 4 < c) ? (int)sp[e + 4] : N;
                int i5 = (e + 5 < c) ? (int)sp[e + 5] : N;
                int i6 = (e + 6 < c) ? (int)sp[e + 6] : N;
                int i7 = (e + 7 < c) ? (int)sp[e + 7] : N;
                U3 v0 = ldrow(g, i0, j);
                U3 v1 = ldrow(g, i1, j);
                U3 v2 = ldrow(g, i2, j);
                U3 v3 = ldrow(g, i3, j);
                U3 v4 = ldrow(g, i4, j);
                U3 v5 = ldrow(g, i5, j);
                U3 v6 = ldrow(g, i6, j);
                U3 v7 = ldrow(g, i7, j);
                acc6(sA, v0); acc6(sB, v1); acc6(sA, v2); acc6(sB, v3);
                acc6(sA, v4); acc6(sB, v5); acc6(sA, v6); acc6(sB, v7);
            }
            float inv = (c > 0) ? 1.f / (float)c : 0.f;
#pragma unroll
            for (int k = 0; k < 6; k++) a[k] += (sA[k] + sB[k]) * inv;
        }
        float o0 = fmaxf(p0.x + a[0], 0.f);
        float o1 = fmaxf(p0.y + a[1], 0.f);
        float o2 = fmaxf(p1.x + a[2], 0.f);
        float o3 = fmaxf(p1.y + a[3], 0.f);
        float o4 = fmaxf(p2.x + a[4], 0.f);
        float o5 = fmaxf(p2.y + a[5], 0.f);
        if constexpr (GEMM) {
            float* dr = &sout[grp][6 * j];
            dr[0]=o0; dr[1]=o1; dr[2]=o2; dr[3]=o3; dr[4]=o4; dr[5]=o5;
        } else {
            if (valid) {
                float* dr = dout + (size_t)n * DN + 6 * j;
                *(float2*)(dr)     = make_float2(o0, o1);
                *(float2*)(dr + 2) = make_float2(o2, o3);
                *(float2*)(dr + 4) = make_float2(o4, o5);
            }
        }
    }

    if constexpr (!GEMM) return;
    __syncthreads();

    // ---- gemm phase ----
    {
        int l = t & 63;
        int w = t >> 6;
        const float* srow = &sout[l & 15][0];
        int mbase = blockIdx.x * 16 + ((l >> 4) << 2);
        int k0 = (l >> 4) * 8;
        short8v ah[3], al[3];
#pragma unroll
        for (int ks = 0; ks < 3; ks++) {
            float4 xa = *(const float4*)(srow + k0 + 32 * ks);
            float4 xb = *(const float4*)(srow + k0 + 32 * ks + 4);
            cvt8(xa, xb, ah[ks], al[ks]);
        }
        int ctS, ctC;
        ctS = (w < 2) ? 5 * w : 10 + 4 * (w - 2);
        ctC = (w < 2) ? 5 : 4;
        for (int ci = 0; ci < ctC; ci++) {
            int ct = ctS + ci;
            f32x4 hh = {0.f,0.f,0.f,0.f}, hl_ = {0.f,0.f,0.f,0.f}, lh = {0.f,0.f,0.f,0.f};
#pragma unroll
            for (int ks = 0; ks < 3; ks++) {
                size_t base = ((size_t)(ct * 3 + ks) * 64 + l) * 8;
                short8v bh = *(const short8v*)(Bph + base);
                short8v bl = *(const short8v*)(Bpl + base);
                hh  = MFMA16(ah[ks], bh, hh, 0, 0, 0);
                hl_ = MFMA16(ah[ks], bl, hl_, 0, 0, 0);
                lh  = MFMA16(al[ks], bh, lh, 0, 0, 0);
            }
            f32x4 acc = hh + hl_ + lh;
            int mat = ct / 6;
            int col = (ct % 6) * 16 + (l & 15);
            if (mat == 0) {
                float bv = bias[col];
#pragma unroll
                for (int r = 0; r < 4; r++) {
                    int m = mbase + r;
                    if (m < N) hrootOut[(size_t)m * DN + col] = acc[r] + bv;
                }
            } else {
                ushort_t* g = (mat == 1) ? g0Out : g1Out;
#pragma unroll
                for (int r = 0; r < 4; r++) {
                    int m = mbase + r;
                    if (m < N) g[(size_t)m * DN + col] = f2bf(acc[r]);
                }
            }
        }
    }
}

extern "C" void kernel_launch(void* const* d_in, const int* in_sizes, int n_in,
                              void* d_out, int out_size, void* d_ws, size_t ws_size,
                              hipStream_t stream) {
    const float* x    = (const float*)d_in[0];
    const int*   ei   = (const int*)d_in[1];
    const float* ea   = (const float*)d_in[2];
    const float* Wf   = (const float*)d_in[3];
    const float* bf   = (const float*)d_in[4];
    const float* W    = (const float*)d_in[5];
    const float* root = (const float*)d_in[6];
    const float* bias = (const float*)d_in[7];
    float* out = (float*)d_out;

    int N = in_sizes[0] / FIN;  // 50000
    int E = in_sizes[1] / 2;    // 800000
    int nbins = 2 * N;
    int PS = (N + 7) / 8;       // dst partition size
    size_t NR = (size_t)(N + 1) * DN;   // g tables have a zero row at index N

    int* cnt        = (int*)d_ws;            // [2N]
    int* total      = cnt + nbins;           // [1]
    int* rowstart   = cnt + nbins + 4;       // [2N]
    int* fillptr    = rowstart + nbins;      // [2N]
    uint_t* kdx     = (uint_t*)(fillptr + nbins);  // [E] dst | r<<16
    ushort_t* kdy   = (ushort_t*)(kdx + E);        // [E] src (ushort)
    ushort_t* srcs  = kdy + E;                     // [E] (ushort)
    ushort_t* Bph   = (ushort_t*)(((uintptr_t)(srcs + E) + 15) & ~(uintptr_t)15);  // [54*512]
    ushort_t* Bpl   = Bph + 54 * 512;
    ushort_t* Wfh   = Bpl + 54 * 512;        // [24*512]
    ushort_t* Wfl   = Wfh + 24 * 512;
    float* hrootA   = (float*)(Wfl + 24 * 512);            // [N*96] f32
    ushort_t* g0A   = (ushort_t*)(hrootA + (size_t)N * DN);  // [(N+1)*96] bf16
    ushort_t* g1A   = g0A + NR;
    float* hrootB   = (float*)(g1A + NR);                  // [N*96] f32
    ushort_t* g0B   = (ushort_t*)(hrootB + (size_t)N * DN);
    ushort_t* g1B   = g0B + NR;

    hipMemsetAsync(cnt, 0, (size_t)(nbins + 1) * sizeof(int), stream);

    int KD_BLKS = (E + 255) / 256;          // 3125
    int nchunk = (E + 2047) / 2048;         // 391
    int PART_BLKS = nchunk * 8;             // 3128
    int blk64 = (N + 63) / 64;              // 782
    int blk16 = (N + 15) / 16;              // 3125

    // K0: kd build + weight pack + zero rows (all independent)
    prep_kernel<<<KD_BLKS + 78 + 2, 256, 0, stream>>>(
        ei, ea, kdx, kdy, root, W, Wf, Bph, Bpl, Wfh, Wfl,
        g0A, g1A, g0B, g1B, E, N, KD_BLKS);
    // K1: XCD-partitioned histogram
    hist_part<<<PART_BLKS, 256, 0, stream>>>(kdx, cnt, E, N, PS);
    // K2: offsets
    offsets_kernel<<<(nbins + 255) / 256, 256, 0, stream>>>(cnt, total, rowstart, fillptr, nbins);
    // K3: XCD-partitioned CSR fill (ushort srcs)
    fill_part<<<PART_BLKS, 256, 0, stream>>>(kdx, kdy, fillptr, srcs, E, N, PS);
    // L0: lin+gemm from x -> set A
    lin_gemm<<<blk64, 256, 0, stream>>>(
        x, Wfh, Wfl, Bph, Bpl, bf, bias, hrootA, g0A, g1A, N);
    // L1: gather A -> gemm -> set B
    layer_kernel<1><<<blk16, 256, 0, stream>>>(
        hrootA, (const uint_t*)g0A, (const uint_t*)g1A, rowstart, cnt, srcs,
        Bph, Bpl, bias, hrootB, g0B, g1B, nullptr, N);
    // L2: gather B -> gemm -> set A
    layer_kernel<1><<<blk16, 256, 0, stream>>>(
        hrootB, (const uint_t*)g0B, (const uint_t*)g1B, rowstart, cnt, srcs,
        Bph, Bpl, bias, hrootA, g0A, g1A, nullptr, N);
    // L3: gather A -> d_out
    layer_kernel<0><<<blk16, 256, 0, stream>>>(
        hrootA, (const uint_t*)g0A, (const uint_t*)g1A, rowstart, cnt, srcs,
        nullptr, nullptr, nullptr, nullptr, nullptr, nullptr, out, N);
}

// Round 13
// 287.283 us; speedup vs baseline: 1.0255x; 1.0255x over previous
//
#include <hip/hip_runtime.h>

#define DN 96
#define FIN 128

typedef unsigned int uint_t;
typedef unsigned short ushort_t;

typedef __attribute__((ext_vector_type(8))) short short8v;  // 8 bf16 (4 VGPRs)
typedef __attribute__((ext_vector_type(4))) float f32x4;

#define MFMA16 __builtin_amdgcn_mfma_f32_16x16x32_bf16

struct __align__(4) U3 { uint_t x, y, z; };

__device__ __forceinline__ ushort_t f2bf(float f) {
    uint_t u = __float_as_uint(f);
    uint_t r = (u + 0x7FFFu + ((u >> 16) & 1u)) >> 16;
    return (ushort_t)r;
}
__device__ __forceinline__ float bf2f(ushort_t h) { return __uint_as_float(((uint_t)h) << 16); }
__device__ __forceinline__ float bf_lo(uint_t u) { return __uint_as_float(u << 16); }
__device__ __forceinline__ float bf_hi(uint_t u) { return __uint_as_float(u & 0xFFFF0000u); }

__device__ __forceinline__ U3 ldrow(const uint_t* __restrict__ g, int idx, int j) {
    return *(const U3*)(g + (size_t)idx * 48 + 3 * j);
}
__device__ __forceinline__ void acc6(float* s, U3 v) {
    s[0] += bf_lo(v.x); s[1] += bf_hi(v.x);
    s[2] += bf_lo(v.y); s[3] += bf_hi(v.y);
    s[4] += bf_lo(v.z); s[5] += bf_hi(v.z);
}

// ---------- prep: kd build (atomics-free) + weight pack + zero rows, one launch ----------
// kdx[e] = dst | r<<16 ; kdy[e] = src (ushort, N < 65536).

__global__ __launch_bounds__(256) void prep_kernel(
    const int* __restrict__ ei, const float* __restrict__ ea,
    uint_t* __restrict__ kdx, ushort_t* __restrict__ kdy,
    const float* __restrict__ root, const float* __restrict__ W, const float* __restrict__ Wf,
    ushort_t* __restrict__ Bph, ushort_t* __restrict__ Bpl,
    ushort_t* __restrict__ Wfh, ushort_t* __restrict__ Wfl,
    ushort_t* g0A, ushort_t* g1A, ushort_t* g0B, ushort_t* g1B,
    int E, int N, int KD_BLKS)
{
    int bid = blockIdx.x;
    int t = threadIdx.x;
    if (bid < KD_BLKS) {
        int e = bid * 256 + t;
        if (e < E) {
            int src = ei[e];
            int dst = ei[E + e];
            float2 a = *(const float2*)(ea + 2 * e);
            int r = (a.y > a.x) ? 1 : 0;   // argmax over 2, first-max tie -> 0
            kdx[e] = (uint_t)dst | ((uint_t)r << 16);
            kdy[e] = (ushort_t)src;
        }
    } else if (bid < KD_BLKS + 78) {
        if (t >= 64) return;
        int l = t;
        int fid = bid - KD_BLKS;
        if (fid < 54) {
            int ct = fid / 3, ks = fid % 3;
            int mat = ct / 6, cw = ct % 6;
            const float* M = (mat == 0) ? root : (W + (size_t)(mat - 1) * DN * DN);
            int k0 = 32 * ks + (l >> 4) * 8;
            int col = 16 * cw + (l & 15);
#pragma unroll
            for (int j = 0; j < 8; j++) {
                float v = M[(size_t)(k0 + j) * DN + col];
                ushort_t h = f2bf(v);
                size_t idx = ((size_t)fid * 64 + l) * 8 + j;
                Bph[idx] = h;
                Bpl[idx] = f2bf(v - bf2f(h));
            }
        } else {
            int f2 = fid - 54;
            int ct = f2 >> 2, ks = f2 & 3;
            int k0 = 32 * ks + (l >> 4) * 8;
            int col = 16 * ct + (l & 15);
#pragma unroll
            for (int j = 0; j < 8; j++) {
                float v = Wf[(size_t)col * FIN + k0 + j];
                ushort_t h = f2bf(v);
                size_t idx = ((size_t)f2 * 64 + l) * 8 + j;
                Wfh[idx] = h;
                Wfl[idx] = f2bf(v - bf2f(h));
            }
        }
    } else {
        // zero row N of the 4 g tables (clamped-gather target)
        int pair = bid - (KD_BLKS + 78);   // 0 or 1
        ushort_t* ga = pair ? g0B : g0A;
        ushort_t* gb = pair ? g1B : g1A;
        if (t < 96) ga[(size_t)N * DN + t] = 0;
        else if (t < 192) gb[(size_t)N * DN + (t - 96)] = 0;
    }
}

// ---------- XCD-partitioned hist ----------

__global__ __launch_bounds__(256) void hist_part(const uint_t* __restrict__ kdx,
                                                 int* __restrict__ cnt, int E, int N, int PS) {
    int p = blockIdx.x & 7;
    int c = blockIdx.x >> 3;
    int base = c * 2048 + threadIdx.x;
#pragma unroll
    for (int i = 0; i < 8; i++) {
        int e = base + i * 256;
        if (e < E) {
            uint_t v = kdx[e];
            int dst = v & 0xFFFF;
            if (dst / PS == p) {
                int r = (v >> 16) & 1;
                atomicAdd(&cnt[r * N + dst], 1);
            }
        }
    }
}

__global__ void offsets_kernel(const int* __restrict__ cnt, int* __restrict__ total,
                               int* __restrict__ rowstart, int* __restrict__ fillptr,
                               int nbins) {
    __shared__ int sd[256];
    __shared__ int sbase;
    int t = threadIdx.x;
    int b = blockIdx.x * 256 + t;
    int v = (b < nbins) ? cnt[b] : 0;
    sd[t] = v;
    __syncthreads();
    for (int off = 1; off < 256; off <<= 1) {
        int add = (t >= off) ? sd[t - off] : 0;
        __syncthreads();
        sd[t] += add;
        __syncthreads();
    }
    if (t == 255) sbase = atomicAdd(total, sd[255]);
    __syncthreads();
    if (b < nbins) {
        int s = sbase + sd[t] - v;  // exclusive
        rowstart[b] = s;
        fillptr[b] = s;
    }
}

// ---------- split-bf16 A-fragment conversion ----------

__device__ __forceinline__ void cvt8(float4 x, float4 y, short8v& hi, short8v& lo) {
    union { short8v v; ushort_t u[8]; } H, L;
    float f[8] = {x.x, x.y, x.z, x.w, y.x, y.y, y.z, y.w};
#pragma unroll
    for (int j = 0; j < 8; j++) {
        ushort_t h = f2bf(f[j]);
        H.u[j] = h;
        L.u[j] = f2bf(f[j] - bf2f(h));
    }
    hi = H.v; lo = L.v;
}

// ---------- fused fill + lin_gemm (one launch for overlap; 6.4 KB LDS) ----------
// blocks [0, FILL_BLKS): XCD-partitioned CSR fill (latency-bound, 8 blocks/CU).
// blocks [FILL_BLKS, +blk16): 16-node lin tile: h=relu(x@Wf^T+bf) via MFMA
// (6 col-tiles split 2/2/1/1 over 4 waves; each wave loads the same L1-resident
// x slab), then conv-gemm (18 col-tiles split 5/5/4/4).

__global__ __launch_bounds__(256) void fill_lin(
    const uint_t* __restrict__ kdx, const ushort_t* __restrict__ kdy,
    int* __restrict__ fillptr, ushort_t* __restrict__ srcs,
    const float* __restrict__ xin,
    const ushort_t* __restrict__ WfH, const ushort_t* __restrict__ WfL,
    const ushort_t* __restrict__ Bph, const ushort_t* __restrict__ Bpl,
    const float* __restrict__ bfv, const float* __restrict__ bias,
    float* __restrict__ hrootOut, ushort_t* __restrict__ g0Out, ushort_t* __restrict__ g1Out,
    int E, int N, int PS, int FILL_BLKS)
{
    __shared__ float sout[16][100];   // pad breaks power-of-2 bank stride
    int t = threadIdx.x;

    if (blockIdx.x < FILL_BLKS) {
        int p = blockIdx.x & 7;
        int c = blockIdx.x >> 3;
        int base = c * 2048 + t;
#pragma unroll
        for (int i = 0; i < 8; i++) {
            int e = base + i * 256;
            if (e < E) {
                uint_t v = kdx[e];
                int dst = v & 0xFFFF;
                if (dst / PS == p) {
                    int r = (v >> 16) & 1;
                    int pos = atomicAdd(&fillptr[r * N + dst], 1);
                    srcs[pos] = kdy[e];
                }
            }
        }
        return;
    }

    int bid2 = blockIdx.x - FILL_BLKS;
    int l = t & 63;
    int w = t >> 6;

    // ---- lin phase: all 4 waves share the same 16 rows ----
    {
        int slab = bid2 * 16;
        int row = slab + (l & 15);
        if (row >= N) row = N - 1;
        const float* xrow = xin + (size_t)row * FIN + ((l >> 4) * 8);
        short8v ah4[4], al4[4];
#pragma unroll
        for (int ks = 0; ks < 4; ks++) {
            float4 xa = *(const float4*)(xrow + 32 * ks);
            float4 xb = *(const float4*)(xrow + 32 * ks + 4);
            cvt8(xa, xb, ah4[ks], al4[ks]);
        }
        int nct = (w < 2) ? 2 : 1;
        for (int ci = 0; ci < nct; ci++) {
            int ct = w + ci * 4;   // w0:{0,4} w1:{1,5} w2:{2} w3:{3}
            f32x4 hh = {0.f,0.f,0.f,0.f}, hl_ = {0.f,0.f,0.f,0.f}, lh = {0.f,0.f,0.f,0.f};
#pragma unroll
            for (int ks = 0; ks < 4; ks++) {
                size_t base = ((size_t)(ct * 4 + ks) * 64 + l) * 8;
                short8v bh = *(const short8v*)(WfH + base);
                short8v bl = *(const short8v*)(WfL + base);
                hh  = MFMA16(ah4[ks], bh, hh, 0, 0, 0);
                hl_ = MFMA16(ah4[ks], bl, hl_, 0, 0, 0);
                lh  = MFMA16(al4[ks], bh, lh, 0, 0, 0);
            }
            f32x4 acc = hh + hl_ + lh;
            int col = ct * 16 + (l & 15);
            float bv = bfv[col];
            int lr0 = (l >> 4) * 4;
#pragma unroll
            for (int r = 0; r < 4; r++) {
                float v = acc[r] + bv;
                sout[lr0 + r][col] = v > 0.f ? v : 0.f;
            }
        }
    }
    __syncthreads();

    // ---- conv gemm phase ----
    {
        const float* srow = &sout[l & 15][0];
        int mbase = bid2 * 16 + ((l >> 4) << 2);
        int k0 = (l >> 4) * 8;
        short8v ah[3], al[3];
#pragma unroll
        for (int ks = 0; ks < 3; ks++) {
            float4 xa = *(const float4*)(srow + k0 + 32 * ks);
            float4 xb = *(const float4*)(srow + k0 + 32 * ks + 4);
            cvt8(xa, xb, ah[ks], al[ks]);
        }
        int ctS = (w < 2) ? 5 * w : 10 + 4 * (w - 2);
        int ctC = (w < 2) ? 5 : 4;
        for (int ci = 0; ci < ctC; ci++) {
            int ct = ctS + ci;
            f32x4 hh = {0.f,0.f,0.f,0.f}, hl_ = {0.f,0.f,0.f,0.f}, lh = {0.f,0.f,0.f,0.f};
#pragma unroll
            for (int ks = 0; ks < 3; ks++) {
                size_t base = ((size_t)(ct * 3 + ks) * 64 + l) * 8;
                short8v bh = *(const short8v*)(Bph + base);
                short8v bl = *(const short8v*)(Bpl + base);
                hh  = MFMA16(ah[ks], bh, hh, 0, 0, 0);
                hl_ = MFMA16(ah[ks], bl, hl_, 0, 0, 0);
                lh  = MFMA16(al[ks], bh, lh, 0, 0, 0);
            }
            f32x4 acc = hh + hl_ + lh;
            int mat = ct / 6;
            int col = (ct % 6) * 16 + (l & 15);
            if (mat == 0) {
                float bv = bias[col];
#pragma unroll
                for (int r = 0; r < 4; r++) {
                    int m = mbase + r;
                    if (m < N) hrootOut[(size_t)m * DN + col] = acc[r] + bv;
                }
            } else {
                ushort_t* g = (mat == 1) ? g0Out : g1Out;
#pragma unroll
                for (int r = 0; r < 4; r++) {
                    int m = mbase + r;
                    if (m < N) g[(size_t)m * DN + col] = f2bf(acc[r]);
                }
            }
        }
    }
}

// ---------- fused gather(+gemm) layer: 256 thr / 16 nodes ----------

template <int GEMM>
__global__ __launch_bounds__(256) void layer_kernel(
    const float* __restrict__ hrootIn,
    const uint_t* __restrict__ g0In, const uint_t* __restrict__ g1In,
    const int* __restrict__ rowstart, const int* __restrict__ cnt,
    const ushort_t* __restrict__ srcs,
    const ushort_t* __restrict__ Bph, const ushort_t* __restrict__ Bpl,
    const float* __restrict__ bias,
    float* __restrict__ hrootOut, ushort_t* __restrict__ g0Out, ushort_t* __restrict__ g1Out,
    float* __restrict__ dout, int N)
{
    __shared__ float sout[16][100];
    int t = threadIdx.x;

    // ---- gather phase ----
    {
        int grp = t >> 4;
        int j = t & 15;
        int n = blockIdx.x * 16 + grp;
        bool valid = n < N;
        int nc = valid ? n : N - 1;

        const float* hr = hrootIn + (size_t)nc * DN + 6 * j;
        float2 p0 = *(const float2*)hr;
        float2 p1 = *(const float2*)(hr + 2);
        float2 p2 = *(const float2*)(hr + 4);

        float a[6] = {0.f,0.f,0.f,0.f,0.f,0.f};
#pragma unroll
        for (int r = 0; r < 2; r++) {
            int c    = valid ? cnt[r * N + nc] : 0;
            int base = valid ? rowstart[r * N + nc] : 0;
            const uint_t* g = r ? g1In : g0In;
            const ushort_t* sp = srcs + base;
            float sA[6] = {0.f,0.f,0.f,0.f,0.f,0.f};
            float sB[6] = {0.f,0.f,0.f,0.f,0.f,0.f};
            for (int e = 0; e < c; e += 8) {
                int i0 = (e + 0 < c) ? (int)sp[e + 0] : N;
                int i1 = (e + 1 < c) ? (int)sp[e + 1] : N;
                int i2 = (e + 2 < c) ? (int)sp[e + 2] : N;
                int i3 = (e + 3 < c) ? (int)sp[e + 3] : N;
                int i4 = (e + 4 < c) ? (int)sp[e + 4] : N;
                int i5 = (e + 5 < c) ? (int)sp[e + 5] : N;
                int i6 = (e + 6 < c) ? (int)sp[e + 6] : N;
                int i7 = (e + 7 < c) ? (int)sp[e + 7] : N;
                U3 v0 = ldrow(g, i0, j);
                U3 v1 = ldrow(g, i1, j);
                U3 v2 = ldrow(g, i2, j);
                U3 v3 = ldrow(g, i3, j);
                U3 v4 = ldrow(g, i4, j);
                U3 v5 = ldrow(g, i5, j);
                U3 v6 = ldrow(g, i6, j);
                U3 v7 = ldrow(g, i7, j);
                acc6(sA, v0); acc6(sB, v1); acc6(sA, v2); acc6(sB, v3);
                acc6(sA, v4); acc6(sB, v5); acc6(sA, v6); acc6(sB, v7);
            }
            float inv = (c > 0) ? 1.f / (float)c : 0.f;
#pragma unroll
            for (int k = 0; k < 6; k++) a[k] += (sA[k] + sB[k]) * inv;
        }
        float o0 = fmaxf(p0.x + a[0], 0.f);
        float o1 = fmaxf(p0.y + a[1], 0.f);
        float o2 = fmaxf(p1.x + a[2], 0.f);
        float o3 = fmaxf(p1.y + a[3], 0.f);
        float o4 = fmaxf(p2.x + a[4], 0.f);
        float o5 = fmaxf(p2.y + a[5], 0.f);
        if constexpr (GEMM) {
            float* dr = &sout[grp][6 * j];
            dr[0]=o0; dr[1]=o1; dr[2]=o2; dr[3]=o3; dr[4]=o4; dr[5]=o5;
        } else {
            if (valid) {
                float* dr = dout + (size_t)n * DN + 6 * j;
                *(float2*)(dr)     = make_float2(o0, o1);
                *(float2*)(dr + 2) = make_float2(o2, o3);
                *(float2*)(dr + 4) = make_float2(o4, o5);
            }
        }
    }

    if constexpr (!GEMM) return;
    __syncthreads();

    // ---- gemm phase ----
    {
        int l = t & 63;
        int w = t >> 6;
        const float* srow = &sout[l & 15][0];
        int mbase = blockIdx.x * 16 + ((l >> 4) << 2);
        int k0 = (l >> 4) * 8;
        short8v ah[3], al[3];
#pragma unroll
        for (int ks = 0; ks < 3; ks++) {
            float4 xa = *(const float4*)(srow + k0 + 32 * ks);
            float4 xb = *(const float4*)(srow + k0 + 32 * ks + 4);
            cvt8(xa, xb, ah[ks], al[ks]);
        }
        int ctS = (w < 2) ? 5 * w : 10 + 4 * (w - 2);
        int ctC = (w < 2) ? 5 : 4;
        for (int ci = 0; ci < ctC; ci++) {
            int ct = ctS + ci;
            f32x4 hh = {0.f,0.f,0.f,0.f}, hl_ = {0.f,0.f,0.f,0.f}, lh = {0.f,0.f,0.f,0.f};
#pragma unroll
            for (int ks = 0; ks < 3; ks++) {
                size_t base = ((size_t)(ct * 3 + ks) * 64 + l) * 8;
                short8v bh = *(const short8v*)(Bph + base);
                short8v bl = *(const short8v*)(Bpl + base);
                hh  = MFMA16(ah[ks], bh, hh, 0, 0, 0);
                hl_ = MFMA16(ah[ks], bl, hl_, 0, 0, 0);
                lh  = MFMA16(al[ks], bh, lh, 0, 0, 0);
            }
            f32x4 acc = hh + hl_ + lh;
            int mat = ct / 6;
            int col = (ct % 6) * 16 + (l & 15);
            if (mat == 0) {
                float bv = bias[col];
#pragma unroll
                for (int r = 0; r < 4; r++) {
                    int m = mbase + r;
                    if (m < N) hrootOut[(size_t)m * DN + col] = acc[r] + bv;
                }
            } else {
                ushort_t* g = (mat == 1) ? g0Out : g1Out;
#pragma unroll
                for (int r = 0; r < 4; r++) {
                    int m = mbase + r;
                    if (m < N) g[(size_t)m * DN + col] = f2bf(acc[r]);
                }
            }
        }
    }
}

extern "C" void kernel_launch(void* const* d_in, const int* in_sizes, int n_in,
                              void* d_out, int out_size, void* d_ws, size_t ws_size,
                              hipStream_t stream) {
    const float* x    = (const float*)d_in[0];
    const int*   ei   = (const int*)d_in[1];
    const float* ea   = (const float*)d_in[2];
    const float* Wf   = (const float*)d_in[3];
    const float* bf   = (const float*)d_in[4];
    const float* W    = (const float*)d_in[5];
    const float* root = (const float*)d_in[6];
    const float* bias = (const float*)d_in[7];
    float* out = (float*)d_out;

    int N = in_sizes[0] / FIN;  // 50000
    int E = in_sizes[1] / 2;    // 800000
    int nbins = 2 * N;
    int PS = (N + 7) / 8;       // dst partition size
    size_t NR = (size_t)(N + 1) * DN;   // g tables have a zero row at index N

    int* cnt        = (int*)d_ws;            // [2N]
    int* total      = cnt + nbins;           // [1]
    int* rowstart   = cnt + nbins + 4;       // [2N]
    int* fillptr    = rowstart + nbins;      // [2N]
    uint_t* kdx     = (uint_t*)(fillptr + nbins);  // [E] dst | r<<16
    ushort_t* kdy   = (ushort_t*)(kdx + E);        // [E] src (ushort)
    ushort_t* srcs  = kdy + E;                     // [E] (ushort)
    ushort_t* Bph   = (ushort_t*)(((uintptr_t)(srcs + E) + 15) & ~(uintptr_t)15);  // [54*512]
    ushort_t* Bpl   = Bph + 54 * 512;
    ushort_t* Wfh   = Bpl + 54 * 512;        // [24*512]
    ushort_t* Wfl   = Wfh + 24 * 512;
    float* hrootA   = (float*)(Wfl + 24 * 512);            // [N*96] f32
    ushort_t* g0A   = (ushort_t*)(hrootA + (size_t)N * DN);  // [(N+1)*96] bf16
    ushort_t* g1A   = g0A + NR;
    float* hrootB   = (float*)(g1A + NR);                  // [N*96] f32
    ushort_t* g0B   = (ushort_t*)(hrootB + (size_t)N * DN);
    ushort_t* g1B   = g0B + NR;

    hipMemsetAsync(cnt, 0, (size_t)(nbins + 1) * sizeof(int), stream);

    int KD_BLKS = (E + 255) / 256;          // 3125
    int nchunk = (E + 2047) / 2048;         // 391
    int PART_BLKS = nchunk * 8;             // 3128
    int blk16 = (N + 15) / 16;              // 3125

    // K0: kd build + weight pack + zero rows (all independent)
    prep_kernel<<<KD_BLKS + 78 + 2, 256, 0, stream>>>(
        ei, ea, kdx, kdy, root, W, Wf, Bph, Bpl, Wfh, Wfl,
        g0A, g1A, g0B, g1B, E, N, KD_BLKS);
    // K1: XCD-partitioned histogram
    hist_part<<<PART_BLKS, 256, 0, stream>>>(kdx, cnt, E, N, PS);
    // K2: offsets
    offsets_kernel<<<(nbins + 255) / 256, 256, 0, stream>>>(cnt, total, rowstart, fillptr, nbins);
    // K3: CSR fill overlapped with lin+gemm (L0) in one launch (6.4 KB LDS)
    fill_lin<<<PART_BLKS + blk16, 256, 0, stream>>>(
        kdx, kdy, fillptr, srcs, x, Wfh, Wfl, Bph, Bpl, bf, bias,
        hrootA, g0A, g1A, E, N, PS, PART_BLKS);
    // L1: gather A -> gemm -> set B
    layer_kernel<1><<<blk16, 256, 0, stream>>>(
        hrootA, (const uint_t*)g0A, (const uint_t*)g1A, rowstart, cnt, srcs,
        Bph, Bpl, bias, hrootB, g0B, g1B, nullptr, N);
    // L2: gather B -> gemm -> set A
    layer_kernel<1><<<blk16, 256, 0, stream>>>(
        hrootB, (const uint_t*)g0B, (const uint_t*)g1B, rowstart, cnt, srcs,
        Bph, Bpl, bias, hrootA, g0A, g1A, nullptr, N);
    // L3: gather A -> d_out
    layer_kernel<0><<<blk16, 256, 0, stream>>>(
        hrootA, (const uint_t*)g0A, (const uint_t*)g1A, rowstart, cnt, srcs,
        nullptr, nullptr, nullptr, nullptr, nullptr, nullptr, out, N);
}

// Round 14
// 277.538 us; speedup vs baseline: 1.0615x; 1.0351x over previous
//
#include <hip/hip_runtime.h>

#define DN 96
#define FIN 128

typedef unsigned int uint_t;
typedef unsigned short ushort_t;

typedef __attribute__((ext_vector_type(8))) short short8v;  // 8 bf16 (4 VGPRs)
typedef __attribute__((ext_vector_type(4))) float f32x4;

#define MFMA16 __builtin_amdgcn_mfma_f32_16x16x32_bf16

struct __align__(4) U3 { uint_t x, y, z; };

__device__ __forceinline__ ushort_t f2bf(float f) {
    uint_t u = __float_as_uint(f);
    uint_t r = (u + 0x7FFFu + ((u >> 16) & 1u)) >> 16;
    return (ushort_t)r;
}
__device__ __forceinline__ float bf2f(ushort_t h) { return __uint_as_float(((uint_t)h) << 16); }
__device__ __forceinline__ float bf_lo(uint_t u) { return __uint_as_float(u << 16); }
__device__ __forceinline__ float bf_hi(uint_t u) { return __uint_as_float(u & 0xFFFF0000u); }

__device__ __forceinline__ U3 ldrow(const uint_t* __restrict__ g, int idx, int j) {
    return *(const U3*)(g + (size_t)idx * 48 + 3 * j);
}
__device__ __forceinline__ void acc6(float* s, U3 v) {
    s[0] += bf_lo(v.x); s[1] += bf_hi(v.x);
    s[2] += bf_lo(v.y); s[3] += bf_hi(v.y);
    s[4] += bf_lo(v.z); s[5] += bf_hi(v.z);
}

// ---------- prep: kd build (atomics-free) + weight pack + zero rows, one launch ----------
// kdx[e] = dst | r<<16 ; kdy[e] = src (ushort, N < 65536).

__global__ __launch_bounds__(256) void prep_kernel(
    const int* __restrict__ ei, const float* __restrict__ ea,
    uint_t* __restrict__ kdx, ushort_t* __restrict__ kdy,
    const float* __restrict__ root, const float* __restrict__ W, const float* __restrict__ Wf,
    ushort_t* __restrict__ Bph, ushort_t* __restrict__ Bpl,
    ushort_t* __restrict__ Wfh, ushort_t* __restrict__ Wfl,
    ushort_t* g0A, ushort_t* g1A, ushort_t* g0B, ushort_t* g1B,
    int E, int N, int KD_BLKS)
{
    int bid = blockIdx.x;
    int t = threadIdx.x;
    if (bid < KD_BLKS) {
        int e = bid * 256 + t;
        if (e < E) {
            int src = ei[e];
            int dst = ei[E + e];
            float2 a = *(const float2*)(ea + 2 * e);
            int r = (a.y > a.x) ? 1 : 0;   // argmax over 2, first-max tie -> 0
            kdx[e] = (uint_t)dst | ((uint_t)r << 16);
            kdy[e] = (ushort_t)src;
        }
    } else if (bid < KD_BLKS + 78) {
        if (t >= 64) return;
        int l = t;
        int fid = bid - KD_BLKS;
        if (fid < 54) {
            int ct = fid / 3, ks = fid % 3;
            int mat = ct / 6, cw = ct % 6;
            const float* M = (mat == 0) ? root : (W + (size_t)(mat - 1) * DN * DN);
            int k0 = 32 * ks + (l >> 4) * 8;
            int col = 16 * cw + (l & 15);
#pragma unroll
            for (int j = 0; j < 8; j++) {
                float v = M[(size_t)(k0 + j) * DN + col];
                ushort_t h = f2bf(v);
                size_t idx = ((size_t)fid * 64 + l) * 8 + j;
                Bph[idx] = h;
                Bpl[idx] = f2bf(v - bf2f(h));
            }
        } else {
            int f2 = fid - 54;
            int ct = f2 >> 2, ks = f2 & 3;
            int k0 = 32 * ks + (l >> 4) * 8;
            int col = 16 * ct + (l & 15);
#pragma unroll
            for (int j = 0; j < 8; j++) {
                float v = Wf[(size_t)col * FIN + k0 + j];
                ushort_t h = f2bf(v);
                size_t idx = ((size_t)f2 * 64 + l) * 8 + j;
                Wfh[idx] = h;
                Wfl[idx] = f2bf(v - bf2f(h));
            }
        }
    } else {
        // zero row N of the 4 g tables (clamped-gather target)
        int pair = bid - (KD_BLKS + 78);   // 0 or 1
        ushort_t* ga = pair ? g0B : g0A;
        ushort_t* gb = pair ? g1B : g1A;
        if (t < 96) ga[(size_t)N * DN + t] = 0;
        else if (t < 192) gb[(size_t)N * DN + (t - 96)] = 0;
    }
}

// ---------- XCD-partitioned hist ----------

__global__ __launch_bounds__(256) void hist_part(const uint_t* __restrict__ kdx,
                                                 int* __restrict__ cnt, int E, int N, int PS) {
    int p = blockIdx.x & 7;
    int c = blockIdx.x >> 3;
    int base = c * 2048 + threadIdx.x;
#pragma unroll
    for (int i = 0; i < 8; i++) {
        int e = base + i * 256;
        if (e < E) {
            uint_t v = kdx[e];
            int dst = v & 0xFFFF;
            if (dst / PS == p) {
                int r = (v >> 16) & 1;
                atomicAdd(&cnt[r * N + dst], 1);
            }
        }
    }
}

__global__ void offsets_kernel(const int* __restrict__ cnt, int* __restrict__ total,
                               int* __restrict__ rowstart, int* __restrict__ fillptr,
                               int nbins) {
    __shared__ int sd[256];
    __shared__ int sbase;
    int t = threadIdx.x;
    int b = blockIdx.x * 256 + t;
    int v = (b < nbins) ? cnt[b] : 0;
    sd[t] = v;
    __syncthreads();
    for (int off = 1; off < 256; off <<= 1) {
        int add = (t >= off) ? sd[t - off] : 0;
        __syncthreads();
        sd[t] += add;
        __syncthreads();
    }
    if (t == 255) sbase = atomicAdd(total, sd[255]);
    __syncthreads();
    if (b < nbins) {
        int s = sbase + sd[t] - v;  // exclusive
        rowstart[b] = s;
        fillptr[b] = s;
    }
}

// ---------- split-bf16 A-fragment conversion ----------

__device__ __forceinline__ void cvt8(float4 x, float4 y, short8v& hi, short8v& lo) {
    union { short8v v; ushort_t u[8]; } H, L;
    float f[8] = {x.x, x.y, x.z, x.w, y.x, y.y, y.z, y.w};
#pragma unroll
    for (int j = 0; j < 8; j++) {
        ushort_t h = f2bf(f[j]);
        H.u[j] = h;
        L.u[j] = f2bf(f[j] - bf2f(h));
    }
    hi = H.v; lo = L.v;
}

// ---------- fused fill + lin_gemm (64-node lin tile; round-11 structure + ushort srcs) ----------
// blocks [0, FILL_BLKS): XCD-partitioned CSR fill (ushort scatter, halved bytes).
// blocks [FILL_BLKS, +blk64): 64-node lin tile (wave-local 16 rows) then conv-gemm.

__global__ __launch_bounds__(256) void fill_lin(
    const uint_t* __restrict__ kdx, const ushort_t* __restrict__ kdy,
    int* __restrict__ fillptr, ushort_t* __restrict__ srcs,
    const float* __restrict__ xin,
    const ushort_t* __restrict__ WfH, const ushort_t* __restrict__ WfL,
    const ushort_t* __restrict__ Bph, const ushort_t* __restrict__ Bpl,
    const float* __restrict__ bfv, const float* __restrict__ bias,
    float* __restrict__ hrootOut, ushort_t* __restrict__ g0Out, ushort_t* __restrict__ g1Out,
    int E, int N, int PS, int FILL_BLKS)
{
    __shared__ float sout[4][16][100];
    int t = threadIdx.x;

    if (blockIdx.x < FILL_BLKS) {
        int p = blockIdx.x & 7;
        int c = blockIdx.x >> 3;
        int base = c * 2048 + t;
#pragma unroll
        for (int i = 0; i < 8; i++) {
            int e = base + i * 256;
            if (e < E) {
                uint_t v = kdx[e];
                int dst = v & 0xFFFF;
                if (dst / PS == p) {
                    int r = (v >> 16) & 1;
                    int pos = atomicAdd(&fillptr[r * N + dst], 1);
                    srcs[pos] = kdy[e];
                }
            }
        }
        return;
    }

    int bid2 = blockIdx.x - FILL_BLKS;
    int l = t & 63;
    int w = t >> 6;

    int slab = bid2 * 64 + w * 16;
    int row = slab + (l & 15);
    if (row >= N) row = N - 1;
    const float* xrow = xin + (size_t)row * FIN + ((l >> 4) * 8);
    short8v ah4[4], al4[4];
#pragma unroll
    for (int ks = 0; ks < 4; ks++) {
        float4 xa = *(const float4*)(xrow + 32 * ks);
        float4 xb = *(const float4*)(xrow + 32 * ks + 4);
        cvt8(xa, xb, ah4[ks], al4[ks]);
    }
#pragma unroll
    for (int ct = 0; ct < 6; ct++) {
        f32x4 hh = {0.f,0.f,0.f,0.f}, hl_ = {0.f,0.f,0.f,0.f}, lh = {0.f,0.f,0.f,0.f};
#pragma unroll
        for (int ks = 0; ks < 4; ks++) {
            size_t base = ((size_t)(ct * 4 + ks) * 64 + l) * 8;
            short8v bh = *(const short8v*)(WfH + base);
            short8v bl = *(const short8v*)(WfL + base);
            hh  = MFMA16(ah4[ks], bh, hh, 0, 0, 0);
            hl_ = MFMA16(ah4[ks], bl, hl_, 0, 0, 0);
            lh  = MFMA16(al4[ks], bh, lh, 0, 0, 0);
        }
        f32x4 acc = hh + hl_ + lh;
        int col = ct * 16 + (l & 15);
        float bv = bfv[col];
        int lr0 = (l >> 4) * 4;
#pragma unroll
        for (int r = 0; r < 4; r++) {
            float v = acc[r] + bv;
            sout[w][lr0 + r][col] = v > 0.f ? v : 0.f;
        }
    }
    __syncthreads();

    const float* srow = &sout[w][l & 15][0];
    int mbase = bid2 * 64 + w * 16 + ((l >> 4) << 2);
    int k0 = (l >> 4) * 8;
    short8v ah[3], al[3];
#pragma unroll
    for (int ks = 0; ks < 3; ks++) {
        float4 xa = *(const float4*)(srow + k0 + 32 * ks);
        float4 xb = *(const float4*)(srow + k0 + 32 * ks + 4);
        cvt8(xa, xb, ah[ks], al[ks]);
    }
    for (int ct = 0; ct < 18; ct++) {
        f32x4 hh = {0.f,0.f,0.f,0.f}, hl_ = {0.f,0.f,0.f,0.f}, lh = {0.f,0.f,0.f,0.f};
#pragma unroll
        for (int ks = 0; ks < 3; ks++) {
            size_t base = ((size_t)(ct * 3 + ks) * 64 + l) * 8;
            short8v bh = *(const short8v*)(Bph + base);
            short8v bl = *(const short8v*)(Bpl + base);
            hh  = MFMA16(ah[ks], bh, hh, 0, 0, 0);
            hl_ = MFMA16(ah[ks], bl, hl_, 0, 0, 0);
            lh  = MFMA16(al[ks], bh, lh, 0, 0, 0);
        }
        f32x4 acc = hh + hl_ + lh;
        int mat = ct / 6;
        int col = (ct % 6) * 16 + (l & 15);
        if (mat == 0) {
            float bv = bias[col];
#pragma unroll
            for (int r = 0; r < 4; r++) {
                int m = mbase + r;
                if (m < N) hrootOut[(size_t)m * DN + col] = acc[r] + bv;
            }
        } else {
            ushort_t* g = (mat == 1) ? g0Out : g1Out;
#pragma unroll
            for (int r = 0; r < 4; r++) {
                int m = mbase + r;
                if (m < N) g[(size_t)m * DN + col] = f2bf(acc[r]);
            }
        }
    }
}

// ---------- fused gather(+gemm) layer: 256 thr / 16 nodes ----------

template <int GEMM>
__global__ __launch_bounds__(256) void layer_kernel(
    const float* __restrict__ hrootIn,
    const uint_t* __restrict__ g0In, const uint_t* __restrict__ g1In,
    const int* __restrict__ rowstart, const int* __restrict__ cnt,
    const ushort_t* __restrict__ srcs,
    const ushort_t* __restrict__ Bph, const ushort_t* __restrict__ Bpl,
    const float* __restrict__ bias,
    float* __restrict__ hrootOut, ushort_t* __restrict__ g0Out, ushort_t* __restrict__ g1Out,
    float* __restrict__ dout, int N)
{
    __shared__ float sout[16][100];
    int t = threadIdx.x;

    // ---- gather phase ----
    {
        int grp = t >> 4;
        int j = t & 15;
        int n = blockIdx.x * 16 + grp;
        bool valid = n < N;
        int nc = valid ? n : N - 1;

        const float* hr = hrootIn + (size_t)nc * DN + 6 * j;
        float2 p0 = *(const float2*)hr;
        float2 p1 = *(const float2*)(hr + 2);
        float2 p2 = *(const float2*)(hr + 4);

        float a[6] = {0.f,0.f,0.f,0.f,0.f,0.f};
#pragma unroll
        for (int r = 0; r < 2; r++) {
            int c    = valid ? cnt[r * N + nc] : 0;
            int base = valid ? rowstart[r * N + nc] : 0;
            const uint_t* g = r ? g1In : g0In;
            const ushort_t* sp = srcs + base;
            float sA[6] = {0.f,0.f,0.f,0.f,0.f,0.f};
            float sB[6] = {0.f,0.f,0.f,0.f,0.f,0.f};
            for (int e = 0; e < c; e += 8) {
                int i0 = (e + 0 < c) ? (int)sp[e + 0] : N;
                int i1 = (e + 1 < c) ? (int)sp[e + 1] : N;
                int i2 = (e + 2 < c) ? (int)sp[e + 2] : N;
                int i3 = (e + 3 < c) ? (int)sp[e + 3] : N;
                int i4 = (e + 4 < c) ? (int)sp[e + 4] : N;
                int i5 = (e + 5 < c) ? (int)sp[e + 5] : N;
                int i6 = (e + 6 < c) ? (int)sp[e + 6] : N;
                int i7 = (e + 7 < c) ? (int)sp[e + 7] : N;
                U3 v0 = ldrow(g, i0, j);
                U3 v1 = ldrow(g, i1, j);
                U3 v2 = ldrow(g, i2, j);
                U3 v3 = ldrow(g, i3, j);
                U3 v4 = ldrow(g, i4, j);
                U3 v5 = ldrow(g, i5, j);
                U3 v6 = ldrow(g, i6, j);
                U3 v7 = ldrow(g, i7, j);
                acc6(sA, v0); acc6(sB, v1); acc6(sA, v2); acc6(sB, v3);
                acc6(sA, v4); acc6(sB, v5); acc6(sA, v6); acc6(sB, v7);
            }
            float inv = (c > 0) ? 1.f / (float)c : 0.f;
#pragma unroll
            for (int k = 0; k < 6; k++) a[k] += (sA[k] + sB[k]) * inv;
        }
        float o0 = fmaxf(p0.x + a[0], 0.f);
        float o1 = fmaxf(p0.y + a[1], 0.f);
        float o2 = fmaxf(p1.x + a[2], 0.f);
        float o3 = fmaxf(p1.y + a[3], 0.f);
        float o4 = fmaxf(p2.x + a[4], 0.f);
        float o5 = fmaxf(p2.y + a[5], 0.f);
        if constexpr (GEMM) {
            float* dr = &sout[grp][6 * j];
            dr[0]=o0; dr[1]=o1; dr[2]=o2; dr[3]=o3; dr[4]=o4; dr[5]=o5;
        } else {
            if (valid) {
                float* dr = dout + (size_t)n * DN + 6 * j;
                *(float2*)(dr)     = make_float2(o0, o1);
                *(float2*)(dr + 2) = make_float2(o2, o3);
                *(float2*)(dr + 4) = make_float2(o4, o5);
            }
        }
    }

    if constexpr (!GEMM) return;
    __syncthreads();

    // ---- gemm phase ----
    {
        int l = t & 63;
        int w = t >> 6;
        const float* srow = &sout[l & 15][0];
        int mbase = blockIdx.x * 16 + ((l >> 4) << 2);
        int k0 = (l >> 4) * 8;
        short8v ah[3], al[3];
#pragma unroll
        for (int ks = 0; ks < 3; ks++) {
            float4 xa = *(const float4*)(srow + k0 + 32 * ks);
            float4 xb = *(const float4*)(srow + k0 + 32 * ks + 4);
            cvt8(xa, xb, ah[ks], al[ks]);
        }
        int ctS = (w < 2) ? 5 * w : 10 + 4 * (w - 2);
        int ctC = (w < 2) ? 5 : 4;
        for (int ci = 0; ci < ctC; ci++) {
            int ct = ctS + ci;
            f32x4 hh = {0.f,0.f,0.f,0.f}, hl_ = {0.f,0.f,0.f,0.f}, lh = {0.f,0.f,0.f,0.f};
#pragma unroll
            for (int ks = 0; ks < 3; ks++) {
                size_t base = ((size_t)(ct * 3 + ks) * 64 + l) * 8;
                short8v bh = *(const short8v*)(Bph + base);
                short8v bl = *(const short8v*)(Bpl + base);
                hh  = MFMA16(ah[ks], bh, hh, 0, 0, 0);
                hl_ = MFMA16(ah[ks], bl, hl_, 0, 0, 0);
                lh  = MFMA16(al[ks], bh, lh, 0, 0, 0);
            }
            f32x4 acc = hh + hl_ + lh;
            int mat = ct / 6;
            int col = (ct % 6) * 16 + (l & 15);
            if (mat == 0) {
                float bv = bias[col];
#pragma unroll
                for (int r = 0; r < 4; r++) {
                    int m = mbase + r;
                    if (m < N) hrootOut[(size_t)m * DN + col] = acc[r] + bv;
                }
            } else {
                ushort_t* g = (mat == 1) ? g0Out : g1Out;
#pragma unroll
                for (int r = 0; r < 4; r++) {
                    int m = mbase + r;
                    if (m < N) g[(size_t)m * DN + col] = f2bf(acc[r]);
                }
            }
        }
    }
}

extern "C" void kernel_launch(void* const* d_in, const int* in_sizes, int n_in,
                              void* d_out, int out_size, void* d_ws, size_t ws_size,
                              hipStream_t stream) {
    const float* x    = (const float*)d_in[0];
    const int*   ei   = (const int*)d_in[1];
    const float* ea   = (const float*)d_in[2];
    const float* Wf   = (const float*)d_in[3];
    const float* bf   = (const float*)d_in[4];
    const float* W    = (const float*)d_in[5];
    const float* root = (const float*)d_in[6];
    const float* bias = (const float*)d_in[7];
    float* out = (float*)d_out;

    int N = in_sizes[0] / FIN;  // 50000
    int E = in_sizes[1] / 2;    // 800000
    int nbins = 2 * N;
    int PS = (N + 7) / 8;       // dst partition size
    size_t NR = (size_t)(N + 1) * DN;   // g tables have a zero row at index N

    int* cnt        = (int*)d_ws;            // [2N]
    int* total      = cnt + nbins;           // [1]
    int* rowstart   = cnt + nbins + 4;       // [2N]
    int* fillptr    = rowstart + nbins;      // [2N]
    uint_t* kdx     = (uint_t*)(fillptr + nbins);  // [E] dst | r<<16
    ushort_t* kdy   = (ushort_t*)(kdx + E);        // [E] src (ushort)
    ushort_t* srcs  = kdy + E;                     // [E] (ushort)
    ushort_t* Bph   = (ushort_t*)(((uintptr_t)(srcs + E) + 15) & ~(uintptr_t)15);  // [54*512]
    ushort_t* Bpl   = Bph + 54 * 512;
    ushort_t* Wfh   = Bpl + 54 * 512;        // [24*512]
    ushort_t* Wfl   = Wfh + 24 * 512;
    float* hrootA   = (float*)(Wfl + 24 * 512);            // [N*96] f32
    ushort_t* g0A   = (ushort_t*)(hrootA + (size_t)N * DN);  // [(N+1)*96] bf16
    ushort_t* g1A   = g0A + NR;
    float* hrootB   = (float*)(g1A + NR);                  // [N*96] f32
    ushort_t* g0B   = (ushort_t*)(hrootB + (size_t)N * DN);
    ushort_t* g1B   = g0B + NR;

    hipMemsetAsync(cnt, 0, (size_t)(nbins + 1) * sizeof(int), stream);

    int KD_BLKS = (E + 255) / 256;          // 3125
    int nchunk = (E + 2047) / 2048;         // 391
    int PART_BLKS = nchunk * 8;             // 3128
    int blk64 = (N + 63) / 64;              // 782
    int blk16 = (N + 15) / 16;              // 3125

    // K0: kd build + weight pack + zero rows (all independent)
    prep_kernel<<<KD_BLKS + 78 + 2, 256, 0, stream>>>(
        ei, ea, kdx, kdy, root, W, Wf, Bph, Bpl, Wfh, Wfl,
        g0A, g1A, g0B, g1B, E, N, KD_BLKS);
    // K1: XCD-partitioned histogram
    hist_part<<<PART_BLKS, 256, 0, stream>>>(kdx, cnt, E, N, PS);
    // K2: offsets
    offsets_kernel<<<(nbins + 255) / 256, 256, 0, stream>>>(cnt, total, rowstart, fillptr, nbins);
    // K3: CSR fill (ushort scatter) overlapped with 64-node lin+gemm (L0)
    fill_lin<<<PART_BLKS + blk64, 256, 0, stream>>>(
        kdx, kdy, fillptr, srcs, x, Wfh, Wfl, Bph, Bpl, bf, bias,
        hrootA, g0A, g1A, E, N, PS, PART_BLKS);
    // L1: gather A -> gemm -> set B
    layer_kernel<1><<<blk16, 256, 0, stream>>>(
        hrootA, (const uint_t*)g0A, (const uint_t*)g1A, rowstart, cnt, srcs,
        Bph, Bpl, bias, hrootB, g0B, g1B, nullptr, N);
    // L2: gather B -> gemm -> set A
    layer_kernel<1><<<blk16, 256, 0, stream>>>(
        hrootB, (const uint_t*)g0B, (const uint_t*)g1B, rowstart, cnt, srcs,
        Bph, Bpl, bias, hrootA, g0A, g1A, nullptr, N);
    // L3: gather A -> d_out
    layer_kernel<0><<<blk16, 256, 0, stream>>>(
        hrootA, (const uint_t*)g0A, (const uint_t*)g1A, rowstart, cnt, srcs,
        nullptr, nullptr, nullptr, nullptr, nullptr, nullptr, out, N);
}

// Round 15
// 264.570 us; speedup vs baseline: 1.1135x; 1.0490x over previous
//
#include <hip/hip_runtime.h>

#define DN 96
#define FIN 128

typedef unsigned int uint_t;
typedef unsigned short ushort_t;

typedef __attribute__((ext_vector_type(8))) short short8v;  // 8 bf16 (4 VGPRs)
typedef __attribute__((ext_vector_type(4))) float f32x4;

#define MFMA16 __builtin_amdgcn_mfma_f32_16x16x32_bf16

struct __align__(4) U3 { uint_t x, y, z; };

__device__ __forceinline__ ushort_t f2bf(float f) {
    uint_t u = __float_as_uint(f);
    uint_t r = (u + 0x7FFFu + ((u >> 16) & 1u)) >> 16;
    return (ushort_t)r;
}
__device__ __forceinline__ float bf2f(ushort_t h) { return __uint_as_float(((uint_t)h) << 16); }
__device__ __forceinline__ float bf_lo(uint_t u) { return __uint_as_float(u << 16); }
__device__ __forceinline__ float bf_hi(uint_t u) { return __uint_as_float(u & 0xFFFF0000u); }

__device__ __forceinline__ U3 ldrow(const uint_t* __restrict__ g, int idx, int j) {
    return *(const U3*)(g + (size_t)idx * 48 + 3 * j);
}
__device__ __forceinline__ void acc6(float* s, U3 v) {
    s[0] += bf_lo(v.x); s[1] += bf_hi(v.x);
    s[2] += bf_lo(v.y); s[3] += bf_hi(v.y);
    s[4] += bf_lo(v.z); s[5] += bf_hi(v.z);
}

// ---------- prep: kd build (atomics-free) + weight pack + zero rows, one launch ----------
// kdx[e] = dst | r<<16 ; kdy[e] = src (ushort, N < 65536).

__global__ __launch_bounds__(256) void prep_kernel(
    const int* __restrict__ ei, const float* __restrict__ ea,
    uint_t* __restrict__ kdx, ushort_t* __restrict__ kdy,
    const float* __restrict__ root, const float* __restrict__ W, const float* __restrict__ Wf,
    ushort_t* __restrict__ Bph, ushort_t* __restrict__ Bpl,
    ushort_t* __restrict__ Wfh, ushort_t* __restrict__ Wfl,
    ushort_t* g0A, ushort_t* g1A, ushort_t* g0B, ushort_t* g1B,
    int E, int N, int KD_BLKS)
{
    int bid = blockIdx.x;
    int t = threadIdx.x;
    if (bid < KD_BLKS) {
        int e = bid * 256 + t;
        if (e < E) {
            int src = ei[e];
            int dst = ei[E + e];
            float2 a = *(const float2*)(ea + 2 * e);
            int r = (a.y > a.x) ? 1 : 0;   // argmax over 2, first-max tie -> 0
            kdx[e] = (uint_t)dst | ((uint_t)r << 16);
            kdy[e] = (ushort_t)src;
        }
    } else if (bid < KD_BLKS + 78) {
        if (t >= 64) return;
        int l = t;
        int fid = bid - KD_BLKS;
        if (fid < 54) {
            int ct = fid / 3, ks = fid % 3;
            int mat = ct / 6, cw = ct % 6;
            const float* M = (mat == 0) ? root : (W + (size_t)(mat - 1) * DN * DN);
            int k0 = 32 * ks + (l >> 4) * 8;
            int col = 16 * cw + (l & 15);
#pragma unroll
            for (int j = 0; j < 8; j++) {
                float v = M[(size_t)(k0 + j) * DN + col];
                ushort_t h = f2bf(v);
                size_t idx = ((size_t)fid * 64 + l) * 8 + j;
                Bph[idx] = h;
                Bpl[idx] = f2bf(v - bf2f(h));
            }
        } else {
            int f2 = fid - 54;
            int ct = f2 >> 2, ks = f2 & 3;
            int k0 = 32 * ks + (l >> 4) * 8;
            int col = 16 * ct + (l & 15);
#pragma unroll
            for (int j = 0; j < 8; j++) {
                float v = Wf[(size_t)col * FIN + k0 + j];
                ushort_t h = f2bf(v);
                size_t idx = ((size_t)f2 * 64 + l) * 8 + j;
                Wfh[idx] = h;
                Wfl[idx] = f2bf(v - bf2f(h));
            }
        }
    } else {
        // zero row N of the 4 g tables (clamped-gather target)
        int pair = bid - (KD_BLKS + 78);   // 0 or 1
        ushort_t* ga = pair ? g0B : g0A;
        ushort_t* gb = pair ? g1B : g1A;
        if (t < 96) ga[(size_t)N * DN + t] = 0;
        else if (t < 192) gb[(size_t)N * DN + (t - 96)] = 0;
    }
}

// ---------- XCD-partitioned hist; atomicAdd's return value = in-bin ordinal ----------

__global__ __launch_bounds__(256) void hist_part(const uint_t* __restrict__ kdx,
                                                 int* __restrict__ cnt,
                                                 ushort_t* __restrict__ eorder,
                                                 int E, int N, int PS) {
    int p = blockIdx.x & 7;
    int c = blockIdx.x >> 3;
    int base = c * 2048 + threadIdx.x;
#pragma unroll
    for (int i = 0; i < 8; i++) {
        int e = base + i * 256;
        if (e < E) {
            uint_t v = kdx[e];
            int dst = v & 0xFFFF;
            if (dst / PS == p) {
                int r = (v >> 16) & 1;
                int old = atomicAdd(&cnt[r * N + dst], 1);
                eorder[e] = (ushort_t)old;
            }
        }
    }
}

__global__ void offsets_kernel(const int* __restrict__ cnt, int* __restrict__ total,
                               int* __restrict__ rowstart, int nbins) {
    __shared__ int sd[256];
    __shared__ int sbase;
    int t = threadIdx.x;
    int b = blockIdx.x * 256 + t;
    int v = (b < nbins) ? cnt[b] : 0;
    sd[t] = v;
    __syncthreads();
    for (int off = 1; off < 256; off <<= 1) {
        int add = (t >= off) ? sd[t - off] : 0;
        __syncthreads();
        sd[t] += add;
        __syncthreads();
    }
    if (t == 255) sbase = atomicAdd(total, sd[255]);
    __syncthreads();
    if (b < nbins) rowstart[b] = sbase + sd[t] - v;  // exclusive
}

// ---------- split-bf16 A-fragment conversion ----------

__device__ __forceinline__ void cvt8(float4 x, float4 y, short8v& hi, short8v& lo) {
    union { short8v v; ushort_t u[8]; } H, L;
    float f[8] = {x.x, x.y, x.z, x.w, y.x, y.y, y.z, y.w};
#pragma unroll
    for (int j = 0; j < 8; j++) {
        ushort_t h = f2bf(f[j]);
        H.u[j] = h;
        L.u[j] = f2bf(f[j] - bf2f(h));
    }
    hi = H.v; lo = L.v;
}

// ---------- fused fill + lin_gemm ----------
// blocks [0, FILL_BLKS): atomic-FREE CSR fill — pos = rowstart[bin] + eorder[e];
// all 8 unrolled iterations fully independent (no RMW chain).
// blocks [FILL_BLKS, +blk64): 64-node lin tile then conv-gemm (round-11 winner).

__global__ __launch_bounds__(256) void fill_lin(
    const uint_t* __restrict__ kdx, const ushort_t* __restrict__ kdy,
    const ushort_t* __restrict__ eorder, const int* __restrict__ rowstart,
    ushort_t* __restrict__ srcs,
    const float* __restrict__ xin,
    const ushort_t* __restrict__ WfH, const ushort_t* __restrict__ WfL,
    const ushort_t* __restrict__ Bph, const ushort_t* __restrict__ Bpl,
    const float* __restrict__ bfv, const float* __restrict__ bias,
    float* __restrict__ hrootOut, ushort_t* __restrict__ g0Out, ushort_t* __restrict__ g1Out,
    int E, int N, int PS, int FILL_BLKS)
{
    __shared__ float sout[4][16][100];
    int t = threadIdx.x;

    if (blockIdx.x < FILL_BLKS) {
        int p = blockIdx.x & 7;
        int c = blockIdx.x >> 3;
        int base = c * 2048 + t;
#pragma unroll
        for (int i = 0; i < 8; i++) {
            int e = base + i * 256;
            if (e < E) {
                uint_t v = kdx[e];
                int dst = v & 0xFFFF;
                if (dst / PS == p) {
                    int r = (v >> 16) & 1;
                    int pos = rowstart[r * N + dst] + (int)eorder[e];
                    srcs[pos] = kdy[e];
                }
            }
        }
        return;
    }

    int bid2 = blockIdx.x - FILL_BLKS;
    int l = t & 63;
    int w = t >> 6;

    int slab = bid2 * 64 + w * 16;
    int row = slab + (l & 15);
    if (row >= N) row = N - 1;
    const float* xrow = xin + (size_t)row * FIN + ((l >> 4) * 8);
    short8v ah4[4], al4[4];
#pragma unroll
    for (int ks = 0; ks < 4; ks++) {
        float4 xa = *(const float4*)(xrow + 32 * ks);
        float4 xb = *(const float4*)(xrow + 32 * ks + 4);
        cvt8(xa, xb, ah4[ks], al4[ks]);
    }
#pragma unroll
    for (int ct = 0; ct < 6; ct++) {
        f32x4 hh = {0.f,0.f,0.f,0.f}, hl_ = {0.f,0.f,0.f,0.f}, lh = {0.f,0.f,0.f,0.f};
#pragma unroll
        for (int ks = 0; ks < 4; ks++) {
            size_t base = ((size_t)(ct * 4 + ks) * 64 + l) * 8;
            short8v bh = *(const short8v*)(WfH + base);
            short8v bl = *(const short8v*)(WfL + base);
            hh  = MFMA16(ah4[ks], bh, hh, 0, 0, 0);
            hl_ = MFMA16(ah4[ks], bl, hl_, 0, 0, 0);
            lh  = MFMA16(al4[ks], bh, lh, 0, 0, 0);
        }
        f32x4 acc = hh + hl_ + lh;
        int col = ct * 16 + (l & 15);
        float bv = bfv[col];
        int lr0 = (l >> 4) * 4;
#pragma unroll
        for (int r = 0; r < 4; r++) {
            float v = acc[r] + bv;
            sout[w][lr0 + r][col] = v > 0.f ? v : 0.f;
        }
    }
    __syncthreads();

    const float* srow = &sout[w][l & 15][0];
    int mbase = bid2 * 64 + w * 16 + ((l >> 4) << 2);
    int k0 = (l >> 4) * 8;
    short8v ah[3], al[3];
#pragma unroll
    for (int ks = 0; ks < 3; ks++) {
        float4 xa = *(const float4*)(srow + k0 + 32 * ks);
        float4 xb = *(const float4*)(srow + k0 + 32 * ks + 4);
        cvt8(xa, xb, ah[ks], al[ks]);
    }
    for (int ct = 0; ct < 18; ct++) {
        f32x4 hh = {0.f,0.f,0.f,0.f}, hl_ = {0.f,0.f,0.f,0.f}, lh = {0.f,0.f,0.f,0.f};
#pragma unroll
        for (int ks = 0; ks < 3; ks++) {
            size_t base = ((size_t)(ct * 3 + ks) * 64 + l) * 8;
            short8v bh = *(const short8v*)(Bph + base);
            short8v bl = *(const short8v*)(Bpl + base);
            hh  = MFMA16(ah[ks], bh, hh, 0, 0, 0);
            hl_ = MFMA16(ah[ks], bl, hl_, 0, 0, 0);
            lh  = MFMA16(al[ks], bh, lh, 0, 0, 0);
        }
        f32x4 acc = hh + hl_ + lh;
        int mat = ct / 6;
        int col = (ct % 6) * 16 + (l & 15);
        if (mat == 0) {
            float bv = bias[col];
#pragma unroll
            for (int r = 0; r < 4; r++) {
                int m = mbase + r;
                if (m < N) hrootOut[(size_t)m * DN + col] = acc[r] + bv;
            }
        } else {
            ushort_t* g = (mat == 1) ? g0Out : g1Out;
#pragma unroll
            for (int r = 0; r < 4; r++) {
                int m = mbase + r;
                if (m < N) g[(size_t)m * DN + col] = f2bf(acc[r]);
            }
        }
    }
}

// ---------- fused gather(+gemm) layer: 256 thr / 16 nodes ----------

template <int GEMM>
__global__ __launch_bounds__(256) void layer_kernel(
    const float* __restrict__ hrootIn,
    const uint_t* __restrict__ g0In, const uint_t* __restrict__ g1In,
    const int* __restrict__ rowstart, const int* __restrict__ cnt,
    const ushort_t* __restrict__ srcs,
    const ushort_t* __restrict__ Bph, const ushort_t* __restrict__ Bpl,
    const float* __restrict__ bias,
    float* __restrict__ hrootOut, ushort_t* __restrict__ g0Out, ushort_t* __restrict__ g1Out,
    float* __restrict__ dout, int N)
{
    __shared__ float sout[16][100];
    int t = threadIdx.x;

    // ---- gather phase ----
    {
        int grp = t >> 4;
        int j = t & 15;
        int n = blockIdx.x * 16 + grp;
        bool valid = n < N;
        int nc = valid ? n : N - 1;

        const float* hr = hrootIn + (size_t)nc * DN + 6 * j;
        float2 p0 = *(const float2*)hr;
        float2 p1 = *(const float2*)(hr + 2);
        float2 p2 = *(const float2*)(hr + 4);

        float a[6] = {0.f,0.f,0.f,0.f,0.f,0.f};
#pragma unroll
        for (int r = 0; r < 2; r++) {
            int c    = valid ? cnt[r * N + nc] : 0;
            int base = valid ? rowstart[r * N + nc] : 0;
            const uint_t* g = r ? g1In : g0In;
            const ushort_t* sp = srcs + base;
            float sA[6] = {0.f,0.f,0.f,0.f,0.f,0.f};
            float sB[6] = {0.f,0.f,0.f,0.f,0.f,0.f};
            for (int e = 0; e < c; e += 8) {
                int i0 = (e + 0 < c) ? (int)sp[e + 0] : N;
                int i1 = (e + 1 < c) ? (int)sp[e + 1] : N;
                int i2 = (e + 2 < c) ? (int)sp[e + 2] : N;
                int i3 = (e + 3 < c) ? (int)sp[e + 3] : N;
                int i4 = (e + 4 < c) ? (int)sp[e + 4] : N;
                int i5 = (e + 5 < c) ? (int)sp[e + 5] : N;
                int i6 = (e + 6 < c) ? (int)sp[e + 6] : N;
                int i7 = (e + 7 < c) ? (int)sp[e + 7] : N;
                U3 v0 = ldrow(g, i0, j);
                U3 v1 = ldrow(g, i1, j);
                U3 v2 = ldrow(g, i2, j);
                U3 v3 = ldrow(g, i3, j);
                U3 v4 = ldrow(g, i4, j);
                U3 v5 = ldrow(g, i5, j);
                U3 v6 = ldrow(g, i6, j);
                U3 v7 = ldrow(g, i7, j);
                acc6(sA, v0); acc6(sB, v1); acc6(sA, v2); acc6(sB, v3);
                acc6(sA, v4); acc6(sB, v5); acc6(sA, v6); acc6(sB, v7);
            }
            float inv = (c > 0) ? 1.f / (float)c : 0.f;
#pragma unroll
            for (int k = 0; k < 6; k++) a[k] += (sA[k] + sB[k]) * inv;
        }
        float o0 = fmaxf(p0.x + a[0], 0.f);
        float o1 = fmaxf(p0.y + a[1], 0.f);
        float o2 = fmaxf(p1.x + a[2], 0.f);
        float o3 = fmaxf(p1.y + a[3], 0.f);
        float o4 = fmaxf(p2.x + a[4], 0.f);
        float o5 = fmaxf(p2.y + a[5], 0.f);
        if constexpr (GEMM) {
            float* dr = &sout[grp][6 * j];
            dr[0]=o0; dr[1]=o1; dr[2]=o2; dr[3]=o3; dr[4]=o4; dr[5]=o5;
        } else {
            if (valid) {
                float* dr = dout + (size_t)n * DN + 6 * j;
                *(float2*)(dr)     = make_float2(o0, o1);
                *(float2*)(dr + 2) = make_float2(o2, o3);
                *(float2*)(dr + 4) = make_float2(o4, o5);
            }
        }
    }

    if constexpr (!GEMM) return;
    __syncthreads();

    // ---- gemm phase ----
    {
        int l = t & 63;
        int w = t >> 6;
        const float* srow = &sout[l & 15][0];
        int mbase = blockIdx.x * 16 + ((l >> 4) << 2);
        int k0 = (l >> 4) * 8;
        short8v ah[3], al[3];
#pragma unroll
        for (int ks = 0; ks < 3; ks++) {
            float4 xa = *(const float4*)(srow + k0 + 32 * ks);
            float4 xb = *(const float4*)(srow + k0 + 32 * ks + 4);
            cvt8(xa, xb, ah[ks], al[ks]);
        }
        int ctS = (w < 2) ? 5 * w : 10 + 4 * (w - 2);
        int ctC = (w < 2) ? 5 : 4;
        for (int ci = 0; ci < ctC; ci++) {
            int ct = ctS + ci;
            f32x4 hh = {0.f,0.f,0.f,0.f}, hl_ = {0.f,0.f,0.f,0.f}, lh = {0.f,0.f,0.f,0.f};
#pragma unroll
            for (int ks = 0; ks < 3; ks++) {
                size_t base = ((size_t)(ct * 3 + ks) * 64 + l) * 8;
                short8v bh = *(const short8v*)(Bph + base);
                short8v bl = *(const short8v*)(Bpl + base);
                hh  = MFMA16(ah[ks], bh, hh, 0, 0, 0);
                hl_ = MFMA16(ah[ks], bl, hl_, 0, 0, 0);
                lh  = MFMA16(al[ks], bh, lh, 0, 0, 0);
            }
            f32x4 acc = hh + hl_ + lh;
            int mat = ct / 6;
            int col = (ct % 6) * 16 + (l & 15);
            if (mat == 0) {
                float bv = bias[col];
#pragma unroll
                for (int r = 0; r < 4; r++) {
                    int m = mbase + r;
                    if (m < N) hrootOut[(size_t)m * DN + col] = acc[r] + bv;
                }
            } else {
                ushort_t* g = (mat == 1) ? g0Out : g1Out;
#pragma unroll
                for (int r = 0; r < 4; r++) {
                    int m = mbase + r;
                    if (m < N) g[(size_t)m * DN + col] = f2bf(acc[r]);
                }
            }
        }
    }
}

extern "C" void kernel_launch(void* const* d_in, const int* in_sizes, int n_in,
                              void* d_out, int out_size, void* d_ws, size_t ws_size,
                              hipStream_t stream) {
    const float* x    = (const float*)d_in[0];
    const int*   ei   = (const int*)d_in[1];
    const float* ea   = (const float*)d_in[2];
    const float* Wf   = (const float*)d_in[3];
    const float* bf   = (const float*)d_in[4];
    const float* W    = (const float*)d_in[5];
    const float* root = (const float*)d_in[6];
    const float* bias = (const float*)d_in[7];
    float* out = (float*)d_out;

    int N = in_sizes[0] / FIN;  // 50000
    int E = in_sizes[1] / 2;    // 800000
    int nbins = 2 * N;
    int PS = (N + 7) / 8;       // dst partition size
    size_t NR = (size_t)(N + 1) * DN;   // g tables have a zero row at index N

    int* cnt        = (int*)d_ws;            // [2N]
    int* total      = cnt + nbins;           // [1]
    int* rowstart   = cnt + nbins + 4;       // [2N]
    uint_t* kdx     = (uint_t*)(rowstart + nbins);  // [E] dst | r<<16
    ushort_t* kdy   = (ushort_t*)(kdx + E);         // [E] src (ushort)
    ushort_t* eorder= kdy + E;                      // [E] in-bin ordinal (ushort)
    ushort_t* srcs  = eorder + E;                   // [E] (ushort)
    ushort_t* Bph   = (ushort_t*)(((uintptr_t)(srcs + E) + 15) & ~(uintptr_t)15);  // [54*512]
    ushort_t* Bpl   = Bph + 54 * 512;
    ushort_t* Wfh   = Bpl + 54 * 512;        // [24*512]
    ushort_t* Wfl   = Wfh + 24 * 512;
    float* hrootA   = (float*)(Wfl + 24 * 512);            // [N*96] f32
    ushort_t* g0A   = (ushort_t*)(hrootA + (size_t)N * DN);  // [(N+1)*96] bf16
    ushort_t* g1A   = g0A + NR;
    float* hrootB   = (float*)(g1A + NR);                  // [N*96] f32
    ushort_t* g0B   = (ushort_t*)(hrootB + (size_t)N * DN);
    ushort_t* g1B   = g0B + NR;

    hipMemsetAsync(cnt, 0, (size_t)(nbins + 1) * sizeof(int), stream);

    int KD_BLKS = (E + 255) / 256;          // 3125
    int nchunk = (E + 2047) / 2048;         // 391
    int PART_BLKS = nchunk * 8;             // 3128
    int blk64 = (N + 63) / 64;              // 782
    int blk16 = (N + 15) / 16;              // 3125

    // K0: kd build + weight pack + zero rows (all independent)
    prep_kernel<<<KD_BLKS + 78 + 2, 256, 0, stream>>>(
        ei, ea, kdx, kdy, root, W, Wf, Bph, Bpl, Wfh, Wfl,
        g0A, g1A, g0B, g1B, E, N, KD_BLKS);
    // K1: XCD-partitioned histogram + per-edge in-bin ordinal
    hist_part<<<PART_BLKS, 256, 0, stream>>>(kdx, cnt, eorder, E, N, PS);
    // K2: offsets (rowstart only; no fillptr needed)
    offsets_kernel<<<(nbins + 255) / 256, 256, 0, stream>>>(cnt, total, rowstart, nbins);
    // K3: atomic-free CSR fill overlapped with 64-node lin+gemm (L0)
    fill_lin<<<PART_BLKS + blk64, 256, 0, stream>>>(
        kdx, kdy, eorder, rowstart, srcs, x, Wfh, Wfl, Bph, Bpl, bf, bias,
        hrootA, g0A, g1A, E, N, PS, PART_BLKS);
    // L1: gather A -> gemm -> set B
    layer_kernel<1><<<blk16, 256, 0, stream>>>(
        hrootA, (const uint_t*)g0A, (const uint_t*)g1A, rowstart, cnt, srcs,
        Bph, Bpl, bias, hrootB, g0B, g1B, nullptr, N);
    // L2: gather B -> gemm -> set A
    layer_kernel<1><<<blk16, 256, 0, stream>>>(
        hrootB, (const uint_t*)g0B, (const uint_t*)g1B, rowstart, cnt, srcs,
        Bph, Bpl, bias, hrootA, g0A, g1A, nullptr, N);
    // L3: gather A -> d_out
    layer_kernel<0><<<blk16, 256, 0, stream>>>(
        hrootA, (const uint_t*)g0A, (const uint_t*)g1A, rowstart, cnt, srcs,
        nullptr, nullptr, nullptr, nullptr, nullptr, nullptr, out, N);
}